// Round 11
// baseline (234.952 us; speedup 1.0000x reference)
//
#include <hip/hip_runtime.h>
#include <math.h>

// TGV-2 PDHG, B=2, H=W=256, T=128.
// R24 = R23 (199.6us, absmax 7.45e-9) with the two per-iteration
// __syncthreads() replaced by PAIRWISE WAVE FLAG-SYNC.
// Evidence: R20/R14/R12/R11 proved the iter cost is the 2x full-block
// rendezvous+drain, not ops/bytes/TLP. The dependency graph only couples
// ADJACENT row-pairs: dual of rows {2w,2w+1} reads rows <=2w+2 (needs wave
// w+1's ub/vb publish); primal reads rows >=2w-1 (needs wave w-1's p,q).
// Protocol per iter: publish ub/vb -> lgkmcnt(0) -> flagA[w]=t; wait
// flagA[w+1]>=t; dual + publish p,q -> lgkmcnt(0) -> flagB[w]=t; wait
// flagB[w-1]>=t; primal. WAR safety (no double-buffer needed): w overwrites
// ub/vb at t+1 only after primal(t), which waited flagB[w-1]>=t, set after
// w-1's dual(t) reads of row 2w were DRAINED by its lgkmcnt(0); w overwrites
// p,q at dual(t+1) only after flagA[w+1]>=t+1, set after w+1's primal(t)
// reads of row 2w+1 were drained. Waves self-organize into a +-1-iter
// pipeline; no 16-wave straggle accumulation.
// Layout: 32 threads/row (lanes 24..31 idle-masked; issue ~25% busy so the
// masked issue is free) -> wave w = exactly rows {2w,2w+1}; 1024 threads,
// 16 waves, 1 block/CU. Valid-px arithmetic, trapezoid gating, interior
// maskless body, tau*f hoist, XCD swizzle, paired ws layout all identical
// to R23 -> absmax must stay exactly 7.450581e-09.
// 16 launches x 8 trapezoid iters; init folded into launch 0; final launch
// stores only u.

namespace {

typedef float v2f __attribute__((ext_vector_type(2)));

constexpr int kN = 2 * 256 * 256;
constexpr float kTau = 0.28867513459481287f;  // 1/sqrt(12) (f32)
constexpr float kSigma = kTau;
constexpr float kInv1pTau = 1.0f / (1.0f + kTau);

constexpr int RR = 32;          // region rows (H)
constexpr int RC = 48;          // region cols (W)
constexpr int A = RR * RC;      // 1536 floats per LDS array
constexpr int PAD = 64;         // rim-overread safety pads (front/back)
constexpr int TILE_R = 16;
constexpr int TILE_C = 32;
constexpr int HALO = 8;         // = iterations per launch
constexpr int NLAUNCH = 128 / HALO;      // 16
constexpr int NTHREADS = 32 * 32;        // 1024 = 16 waves (wave = 2 rows)

__device__ __forceinline__ float4 ld4(const float* p) {
  return *reinterpret_cast<const float4*>(p);
}

// The 8-iteration trapezoid loop with pairwise flag sync.
// M=true: boundary blocks (masks as 0/1 multipliers). M=false: interior
// blocks — masks all 1.0, multiplies removed (bit-exact).
template <bool M>
__device__ __forceinline__ void run8(
    float* ubS, float* vbS, float* p1S, float* p2S, float* q11S, float* q22S,
    float* q12S, volatile int* vA, volatile int* vB, const int w,
    const int lane, const bool active, const int rc, const int r,
    const float alpha0, const float alpha1, const float mD, const float mU,
    const v2f mR, const v2f mL, const v2f fI, v2f& u_, v2f& ub_, v2f& v1_,
    v2f& v2_, v2f& vb1_, v2f& vb2_, v2f& p1_, v2f& p2_, v2f& q11_, v2f& q22_,
    v2f& q12_) {
  for (int t = 0; t < HALO; ++t) {
    // Row-wise trapezoid gating (validated R14/R20); rim rows' garbage is
    // never read by valid outputs.
    const bool pubD = active && (r >= t) && (r <= 31 - t);
    const bool actD = active && (r >= t) && (r <= 30 - t);
    const bool actP = active && (r >= t + 1) && (r <= 30 - t);

    // ---- publish dual-input halos: ub (b64), vb pair (b128) ----
    if (pubD) {
      *reinterpret_cast<v2f*>(ubS + rc) = ub_;
      float4 vp;
      vp.x = vb1_.x; vp.y = vb2_.x; vp.z = vb1_.y; vp.w = vb2_.y;
      *reinterpret_cast<float4*>(vbS + 2 * rc) = vp;
    }
    // drain own DS writes, then raise flagA (always, even if rows gated off)
    asm volatile("s_waitcnt lgkmcnt(0)" ::: "memory");
    if (lane == 0) vA[w] = t;
    // wait for down-neighbor's ub/vb of this iteration
    if (w < 15) {
      while (vA[w + 1] < t) {
      }
    }
    __builtin_amdgcn_sched_barrier(0);

    if (actD) {
      // ---- dual ascent + projections (reads rows r, r+1 only) ----
      const float ubX = ubS[rc + 2];  // right-edge scalar neighbor
      const v2f vbX = *reinterpret_cast<const v2f*>(vbS + 2 * (rc + 2));
      const v2f ubD = *reinterpret_cast<const v2f*>(ubS + rc + RC);
      const float4 vd = ld4(vbS + 2 * (rc + RC));
      v2f vb1D, vb2D;
      vb1D.x = vd.x; vb1D.y = vd.z;
      vb2D.x = vd.y; vb2D.y = vd.w;

      v2f ubr, vb1r, vb2r;  // right-shifted (element e+1)
      ubr.x = ub_.y;   ubr.y = ubX;
      vb1r.x = vb1_.y; vb1r.y = vbX.x;
      vb2r.x = vb2_.y; vb2r.y = vbX.y;

      // p update
      const v2f du1 = M ? mD * (ubD - ub_) : (ubD - ub_);
      const v2f du2 = M ? mR * (ubr - ub_) : (ubr - ub_);
      const v2f pn1 = p1_ + kSigma * (du1 - vb1_);
      const v2f pn2 = p2_ + kSigma * (du2 - vb2_);
      const v2f n2p = pn1 * pn1 + pn2 * pn2;
      v2f sp;
      sp.x = fminf(1.f, alpha1 * __builtin_amdgcn_rsqf(n2p.x));
      sp.y = fminf(1.f, alpha1 * __builtin_amdgcn_rsqf(n2p.y));
      p1_ = pn1 * sp;
      p2_ = pn2 * sp;

      // q update (e11, e22, e12)
      const v2f e11 = M ? mD * (vb1D - vb1_) : (vb1D - vb1_);
      const v2f e22 = M ? mR * (vb2r - vb2_) : (vb2r - vb2_);
      const v2f e12 = M ? 0.5f * (mR * (vb1r - vb1_) + mD * (vb2D - vb2_))
                        : 0.5f * ((vb1r - vb1_) + (vb2D - vb2_));
      const v2f qn1 = q11_ + kSigma * e11;
      const v2f qn2 = q22_ + kSigma * e22;
      const v2f qn3 = q12_ + kSigma * e12;
      const v2f n2q = qn1 * qn1 + qn2 * qn2 + 2.f * (qn3 * qn3);
      v2f sq;
      sq.x = fminf(1.f, alpha0 * __builtin_amdgcn_rsqf(n2q.x));
      sq.y = fminf(1.f, alpha0 * __builtin_amdgcn_rsqf(n2q.y));
      q11_ = qn1 * sq;
      q22_ = qn2 * sq;
      q12_ = qn3 * sq;

      // ---- publish primal halos (new p, q) ----
      *reinterpret_cast<v2f*>(p1S + rc) = p1_;
      *reinterpret_cast<v2f*>(p2S + rc) = p2_;
      *reinterpret_cast<v2f*>(q11S + rc) = q11_;
      *reinterpret_cast<v2f*>(q22S + rc) = q22_;
      *reinterpret_cast<v2f*>(q12S + rc) = q12_;
    }
    // drain own DS ops (writes AND the dual reads of neighbor rows), raise B
    asm volatile("s_waitcnt lgkmcnt(0)" ::: "memory");
    if (lane == 0) vB[w] = t;
    // wait for up-neighbor's p,q of this iteration
    if (w > 0) {
      while (vB[w - 1] < t) {
      }
    }
    __builtin_amdgcn_sched_barrier(0);

    if (actP) {
      // ---- primal descent + over-relaxation (reads rows r-1, r only) ----
      const v2f p1U = *reinterpret_cast<const v2f*>(p1S + rc - RC);
      const v2f q11U = *reinterpret_cast<const v2f*>(q11S + rc - RC);
      const v2f q12U = *reinterpret_cast<const v2f*>(q12S + rc - RC);
      const float p2Ls = p2S[rc - 1];   // left-edge scalar neighbors
      const float q22Ls = q22S[rc - 1];
      const float q12Ls = q12S[rc - 1];

      v2f p2l, q22l, q12l;  // left-shifted (element e-1)
      p2l.x = p2Ls;   p2l.y = p2_.x;
      q22l.x = q22Ls; q22l.y = q22_.x;
      q12l.x = q12Ls; q12l.y = q12_.x;

      const v2f divp = M ? (mD * p1_ + mR * p2_ - (mU * p1U + mL * p2l))
                         : (p1_ + p2_ - (p1U + p2l));
      const v2f un = (u_ + kTau * divp + fI) * kInv1pTau;
      ub_ = 2.f * un - u_;
      u_ = un;

      const v2f c1 = M ? (mD * q11_ + mR * q12_ - (mU * q11U + mL * q12l))
                       : (q11_ + q12_ - (q11U + q12l));
      const v2f c2 = M ? (mD * q12_ + mR * q22_ - (mU * q12U + mL * q22l))
                       : (q12_ + q22_ - (q12U + q22l));
      const v2f v1n = v1_ + kTau * (p1_ + c1);
      const v2f v2n = v2_ + kTau * (p2_ + c2);
      vb1_ = 2.f * v1n - v1_;
      v1_ = v1n;
      vb2_ = 2.f * v2n - v2_;
      v2_ = v2n;
    }
  }
}

// ws layout: 5 pair-arrays of 2*kN floats, interleaved per pixel:
//   pr0=(vb1,vb2) pr1=(p1,p2) pr2=(q11,q22) pr3=(ub,q12) pr4=(v1,v2)
__global__ __launch_bounds__(NTHREADS, 1) void tgv8_kernel(
    const float* __restrict__ f, const float* __restrict__ rp,
    float* __restrict__ ug, float* __restrict__ ws, int t0) {
  float* pr0 = ws + 0 * 2 * kN;  // vb1, vb2
  float* pr1 = ws + 1 * 2 * kN;  // p1, p2
  float* pr2 = ws + 2 * 2 * kN;  // q11, q22
  float* pr3 = ws + 3 * 2 * kN;  // ub, q12
  float* pr4 = ws + 4 * 2 * kN;  // v1, v2

  // LDS: ub (A) + vb-pair (2A) + p1,p2,q11,q22,q12 (5A) = 8A floats + flags
  __shared__ __align__(16) float smem[PAD + 8 * A + PAD];
  __shared__ int flagA[16];
  __shared__ int flagB[16];
  float* ubS = smem + PAD;
  float* vbS = ubS + A;       // interleaved [vb1, vb2] per pixel, 2A floats
  float* p1S = vbS + 2 * A;
  float* p2S = p1S + A;
  float* q11S = p2S + A;
  float* q22S = q11S + A;
  float* q12S = q22S + A;

  // ---- XCD-aware block swizzle (T1, validated R22: -47us) ----
  const int lin = blockIdx.x + 8 * (blockIdx.y + 16 * blockIdx.z);
  const int j = ((lin & 7) << 5) | (lin >> 3);
  const int bz = j >> 7;         // batch
  const int by = (j >> 3) & 15;  // tile row
  const int bx = j & 7;          // tile col

  const int tid = threadIdx.x;
  const int r = tid >> 5;        // region row 0..31 (32 thread slots/row)
  const int s = tid & 31;        // col slot; slots 24..31 are idle-masked
  const bool active = (s < 24);
  const int c = s * 2;           // region col (float2-aligned)
  const int rc = r * RC + c;
  const int w = tid >> 6;        // wave id 0..15; wave w = rows {2w, 2w+1}
  const int lane = tid & 63;

  // flag init (one-time barrier, outside the iteration loop)
  if (tid < 16) {
    flagA[tid] = -1;
    flagB[tid] = -1;
  }
  __syncthreads();

  const int gi = by * TILE_R + r - HALO;  // global row (may be OOB)
  const int gj = bx * TILE_C + c - HALO;  // global col (even)
  const bool inImg = active && ((unsigned)gi < 256u) && ((unsigned)gj < 256u);
  const int base = bz * 65536 + gi * 256 + gj;

  // Interior block: whole region inside (0,255) in both dims -> masks all 1.
  const bool interior = (bx >= 1) && (bx <= 6) && (by >= 1) && (by <= 14);

  const float alpha0 = rp[0];
  const float alpha1 = rp[1];

  // ---- boundary masks as 0/1 multipliers (thread-constant) ----
  const float mD = (gi != 255) ? 1.f : 0.f;  // has down neighbor (H fwd)
  const float mU = (gi != 0) ? 1.f : 0.f;    // has up neighbor (H bwd)
  v2f mR, mL;
  mR.x = (gj + 0 != 255) ? 1.f : 0.f;
  mR.y = (gj + 1 != 255) ? 1.f : 0.f;
  mL.x = (gj != 0) ? 1.f : 0.f;
  mL.y = 1.f;

  // state: one packed v2f per field
  v2f u_, ub_, v1_, v2_, vb1_, vb2_, p1_, p2_, q11_, q22_, q12_, f_;

// paired load/store: [A(x),B(x),A(x+1),B(x+1)] at 2*base (16B aligned)
#define LOADP(va, vb, src)                    \
  {                                           \
    const float4 t4 = ld4((src) + 2 * base);  \
    va.x = t4.x; vb.x = t4.y;                 \
    va.y = t4.z; vb.y = t4.w;                 \
  }
  if (inImg) {
    f_ = *reinterpret_cast<const v2f*>(f + base);
    if (t0 == 0) {
      // PDHG initial state: u = ub = f, everything else zero.
      u_ = f_; ub_ = f_;
      v1_ = 0.f; v2_ = 0.f; vb1_ = 0.f; vb2_ = 0.f;
      p1_ = 0.f; p2_ = 0.f; q11_ = 0.f; q22_ = 0.f; q12_ = 0.f;
    } else {
      LOADP(ub_, q12_, pr3)   // dual-critical fields first
      LOADP(vb1_, vb2_, pr0)
      LOADP(p1_, p2_, pr1)
      LOADP(q11_, q22_, pr2)
      u_ = *reinterpret_cast<const v2f*>(ug + base);  // primal-only
      LOADP(v1_, v2_, pr4)                            // primal-only
    }
  } else {
    f_ = 0.f; u_ = 0.f; ub_ = 0.f;
    v1_ = 0.f; v2_ = 0.f; vb1_ = 0.f; vb2_ = 0.f;
    p1_ = 0.f; p2_ = 0.f; q11_ = 0.f; q22_ = 0.f; q12_ = 0.f;
  }
#undef LOADP

  // Loop-invariant hoist (bit-exact: identical expression, computed once).
  const v2f fI = kTau * f_;

  if (interior) {
    run8<false>(ubS, vbS, p1S, p2S, q11S, q22S, q12S, flagA, flagB, w, lane,
                active, rc, r, alpha0, alpha1, mD, mU, mR, mL, fI, u_, ub_,
                v1_, v2_, vb1_, vb2_, p1_, p2_, q11_, q22_, q12_);
  } else {
    run8<true>(ubS, vbS, p1S, p2S, q11S, q22S, q12S, flagA, flagB, w, lane,
               active, rc, r, alpha0, alpha1, mD, mU, mR, mL, fI, u_, ub_,
               v1_, v2_, vb1_, vb2_, p1_, p2_, q11_, q22_, q12_);
  }

  // ---- store interior 16x32 (exact after 8 iters) ----
  if (r >= HALO && r < HALO + TILE_R && c >= HALO && c < HALO + TILE_C) {
#define STOREP(va, vb, dst)                              \
  {                                                      \
    float4 t4;                                           \
    t4.x = va.x; t4.y = vb.x; t4.z = va.y; t4.w = vb.y;  \
    *reinterpret_cast<float4*>((dst) + 2 * base) = t4;   \
  }
    *reinterpret_cast<v2f*>(ug + base) = u_;
    if (t0 != NLAUNCH - 1) {  // ws is dead after the final launch
      STOREP(vb1_, vb2_, pr0)
      STOREP(p1_, p2_, pr1)
      STOREP(q11_, q22_, pr2)
      STOREP(ub_, q12_, pr3)
      STOREP(v1_, v2_, pr4)
    }
#undef STOREP
  }
}

}  // namespace

extern "C" void kernel_launch(void* const* d_in, const int* in_sizes, int n_in,
                              void* d_out, int out_size, void* d_ws,
                              size_t ws_size, hipStream_t stream) {
  const float* f = (const float*)d_in[0];
  const float* rp = (const float*)d_in[1];  // [alpha0, alpha1]
  // d_in[2] is T = 128 (fixed; trip count must be static for graph capture).

  float* u = (float*)d_out;
  float* ws = (float*)d_ws;

  dim3 grid(256 / TILE_C, 256 / TILE_R, 2);  // 8 x 16 x 2 = 256 blocks
  for (int t = 0; t < NLAUNCH; ++t) {        // 16 launches x 8 iterations
    hipLaunchKernelGGL(tgv8_kernel, grid, dim3(NTHREADS), 0, stream, f, rp, u,
                       ws, t);
  }
}

// Round 12
// 204.807 us; speedup vs baseline: 1.1472x; 1.1472x over previous
//
#include <hip/hip_runtime.h>
#include <math.h>

// TGV-2 PDHG, B=2, H=W=256, T=128.
// R25 = R23 (best: 199.6us, absmax 7.45e-9) + publish-fold into primal.
// R24 post-mortem: pairwise flag-sync was +35us — LDS polling (~120cy/probe)
// + 2x lgkmcnt(0) full drains cost more than the hardware s_barrier. The
// 2-barrier/iter structure with s_barrier is optimal; exec floor = phase
// chain (issue ~0.6us + latency ~0.6us per iter from the R19 scaling fit).
// HALO=16 priced offline with the same fit: iter ~1.77us -> ~250us total,
// rejected.
// This round removes the last naked serial element: R23's per-iter path is
// publish(2 ds_writes)+drain -> bar -> dual -> drain -> bar -> primal. The
// publish range actP(t-1)=[t,31-t] EXACTLY equals what dual(t) reads
// (pubD(t)), so with parity-double-buffered ub/vb the primal phase of t-1
// writes ub_,vb into the write-buffer as they are computed — overlapping
// primal's independent chain instead of serializing before the barrier.
// Loop: prologue publish(all rows)+bar, then {dual, bar, primal+pub, bar}x8.
// WAR across parity buffers is separated by >=2 barriers (both directions
// checked). Same values, same expression order -> output bit-identical
// (absmax must stay exactly 7.450581e-09).
// Everything else = R23: 16 launches x 8 trapezoid iters, region 32x48
// (tile 16x32, halo 8), 256 blocks (1/CU), 768 threads (12 waves), packed
// v2f math, rsq+min projection, row gating, interior-maskless body, tau*f
// hoist, XCD swizzle j=(i%8)*32+i/8, paired-field ws layout, init folded
// into launch 0, final launch stores only u.

namespace {

typedef float v2f __attribute__((ext_vector_type(2)));

constexpr int kN = 2 * 256 * 256;
constexpr float kTau = 0.28867513459481287f;  // 1/sqrt(12) (f32)
constexpr float kSigma = kTau;
constexpr float kInv1pTau = 1.0f / (1.0f + kTau);

constexpr int RR = 32;          // region rows (H)
constexpr int RC = 48;          // region cols (W)
constexpr int A = RR * RC;      // 1536 floats per LDS array
constexpr int PAD = 64;         // rim-overread safety pads (front/back)
constexpr int TILE_R = 16;
constexpr int TILE_C = 32;
constexpr int HALO = 8;         // = iterations per launch
constexpr int NLAUNCH = 128 / HALO;      // 16
constexpr int NTHREADS = RR * (RC / 2);  // 768 = 12 waves

__device__ __forceinline__ float4 ld4(const float* p) {
  return *reinterpret_cast<const float4*>(p);
}

__device__ __forceinline__ void pubUV(float* ubS, float* vbS, int rc,
                                      const v2f ub_, const v2f vb1_,
                                      const v2f vb2_) {
  *reinterpret_cast<v2f*>(ubS + rc) = ub_;
  float4 vp;
  vp.x = vb1_.x; vp.y = vb2_.x; vp.z = vb1_.y; vp.w = vb2_.y;
  *reinterpret_cast<float4*>(vbS + 2 * rc) = vp;
}

// The 8-iteration trapezoid loop, publish folded into primal.
// M=true: boundary blocks (masks as 0/1 multipliers). M=false: interior
// blocks — masks all 1.0, multiplies removed (bit-exact).
template <bool M>
__device__ __forceinline__ void run8(
    float* ubB0, float* ubB1, float* vbB0, float* vbB1, float* p1S,
    float* p2S, float* q11S, float* q22S, float* q12S, const int rc,
    const int r, const float alpha0, const float alpha1, const float mD,
    const float mU, const v2f mR, const v2f mL, const v2f fI, v2f& u_,
    v2f& ub_, v2f& v1_, v2f& v2_, v2f& vb1_, v2f& vb2_, v2f& p1_, v2f& p2_,
    v2f& q11_, v2f& q22_, v2f& q12_) {
  // ---- prologue: publish all rows into buffer 0 ----
  pubUV(ubB0, vbB0, rc, ub_, vb1_, vb2_);
  __syncthreads();

  for (int t = 0; t < HALO; ++t) {
    float* ubS = (t & 1) ? ubB1 : ubB0;  // read buffer (iteration parity)
    float* vbS = (t & 1) ? vbB1 : vbB0;
    float* ubW = (t & 1) ? ubB0 : ubB1;  // write buffer for iter t+1
    float* vbW = (t & 1) ? vbB0 : vbB1;

    // Row-wise trapezoid gating (validated R14/R20).
    const bool actD = (r >= t) && (r <= 30 - t);
    const bool actP = (r >= t + 1) && (r <= 30 - t);

    if (actD) {
      // ---- dual ascent + projections ----
      const float ubX = ubS[rc + 2];  // right-edge scalar neighbor
      const v2f vbX = *reinterpret_cast<const v2f*>(vbS + 2 * (rc + 2));
      const v2f ubD = *reinterpret_cast<const v2f*>(ubS + rc + RC);
      const float4 vd = ld4(vbS + 2 * (rc + RC));
      v2f vb1D, vb2D;
      vb1D.x = vd.x; vb1D.y = vd.z;
      vb2D.x = vd.y; vb2D.y = vd.w;

      v2f ubr, vb1r, vb2r;  // right-shifted (element e+1)
      ubr.x = ub_.y;   ubr.y = ubX;
      vb1r.x = vb1_.y; vb1r.y = vbX.x;
      vb2r.x = vb2_.y; vb2r.y = vbX.y;

      // p update
      const v2f du1 = M ? mD * (ubD - ub_) : (ubD - ub_);
      const v2f du2 = M ? mR * (ubr - ub_) : (ubr - ub_);
      const v2f pn1 = p1_ + kSigma * (du1 - vb1_);
      const v2f pn2 = p2_ + kSigma * (du2 - vb2_);
      const v2f n2p = pn1 * pn1 + pn2 * pn2;
      v2f sp;
      sp.x = fminf(1.f, alpha1 * __builtin_amdgcn_rsqf(n2p.x));
      sp.y = fminf(1.f, alpha1 * __builtin_amdgcn_rsqf(n2p.y));
      p1_ = pn1 * sp;
      p2_ = pn2 * sp;

      // q update (e11, e22, e12)
      const v2f e11 = M ? mD * (vb1D - vb1_) : (vb1D - vb1_);
      const v2f e22 = M ? mR * (vb2r - vb2_) : (vb2r - vb2_);
      const v2f e12 = M ? 0.5f * (mR * (vb1r - vb1_) + mD * (vb2D - vb2_))
                        : 0.5f * ((vb1r - vb1_) + (vb2D - vb2_));
      const v2f qn1 = q11_ + kSigma * e11;
      const v2f qn2 = q22_ + kSigma * e22;
      const v2f qn3 = q12_ + kSigma * e12;
      const v2f n2q = qn1 * qn1 + qn2 * qn2 + 2.f * (qn3 * qn3);
      v2f sq;
      sq.x = fminf(1.f, alpha0 * __builtin_amdgcn_rsqf(n2q.x));
      sq.y = fminf(1.f, alpha0 * __builtin_amdgcn_rsqf(n2q.y));
      q11_ = qn1 * sq;
      q22_ = qn2 * sq;
      q12_ = qn3 * sq;

      // ---- publish primal-input halos (new p, q) ----
      *reinterpret_cast<v2f*>(p1S + rc) = p1_;
      *reinterpret_cast<v2f*>(p2S + rc) = p2_;
      *reinterpret_cast<v2f*>(q11S + rc) = q11_;
      *reinterpret_cast<v2f*>(q22S + rc) = q22_;
      *reinterpret_cast<v2f*>(q12S + rc) = q12_;
    }
    __syncthreads();

    if (actP) {
      // ---- primal descent + over-relaxation ----
      const v2f p1U = *reinterpret_cast<const v2f*>(p1S + rc - RC);
      const v2f q11U = *reinterpret_cast<const v2f*>(q11S + rc - RC);
      const v2f q12U = *reinterpret_cast<const v2f*>(q12S + rc - RC);
      const float p2Ls = p2S[rc - 1];   // left-edge scalar neighbors
      const float q22Ls = q22S[rc - 1];
      const float q12Ls = q12S[rc - 1];

      v2f p2l, q22l, q12l;  // left-shifted (element e-1)
      p2l.x = p2Ls;   p2l.y = p2_.x;
      q22l.x = q22Ls; q22l.y = q22_.x;
      q12l.x = q12Ls; q12l.y = q12_.x;

      const v2f divp = M ? (mD * p1_ + mR * p2_ - (mU * p1U + mL * p2l))
                         : (p1_ + p2_ - (p1U + p2l));
      const v2f un = (u_ + kTau * divp + fI) * kInv1pTau;
      ub_ = 2.f * un - u_;
      u_ = un;

      const v2f c1 = M ? (mD * q11_ + mR * q12_ - (mU * q11U + mL * q12l))
                       : (q11_ + q12_ - (q11U + q12l));
      const v2f c2 = M ? (mD * q12_ + mR * q22_ - (mU * q12U + mL * q22l))
                       : (q12_ + q22_ - (q12U + q22l));
      const v2f v1n = v1_ + kTau * (p1_ + c1);
      const v2f v2n = v2_ + kTau * (p2_ + c2);
      vb1_ = 2.f * v1n - v1_;
      v1_ = v1n;
      vb2_ = 2.f * v2n - v2_;
      v2_ = v2n;

      // ---- folded publish: next iteration's dual inputs ----
      // actP(t) = [t+1, 30-t] == rows read by dual(t+1). Writes overlap the
      // chain above; the trailing barrier drains them.
      pubUV(ubW, vbW, rc, ub_, vb1_, vb2_);
    }
    __syncthreads();
  }
}

// ws layout: 5 pair-arrays of 2*kN floats, interleaved per pixel:
//   pr0=(vb1,vb2) pr1=(p1,p2) pr2=(q11,q22) pr3=(ub,q12) pr4=(v1,v2)
__global__ __launch_bounds__(NTHREADS, 2) void tgv8_kernel(
    const float* __restrict__ f, const float* __restrict__ rp,
    float* __restrict__ ug, float* __restrict__ ws, int t0) {
  float* pr0 = ws + 0 * 2 * kN;  // vb1, vb2
  float* pr1 = ws + 1 * 2 * kN;  // p1, p2
  float* pr2 = ws + 2 * 2 * kN;  // q11, q22
  float* pr3 = ws + 3 * 2 * kN;  // ub, q12
  float* pr4 = ws + 4 * 2 * kN;  // v1, v2

  // LDS: ub x2 (2A) + vb-pair x2 (4A) + p1,p2,q11,q22,q12 (5A) = 11A floats
  __shared__ __align__(16) float smem[PAD + 11 * A + PAD];
  float* ubB0 = smem + PAD;
  float* ubB1 = ubB0 + A;
  float* vbB0 = ubB1 + A;       // interleaved [vb1, vb2] per pixel, 2A each
  float* vbB1 = vbB0 + 2 * A;
  float* p1S = vbB1 + 2 * A;
  float* p2S = p1S + A;
  float* q11S = p2S + A;
  float* q22S = q11S + A;
  float* q12S = q22S + A;

  // ---- XCD-aware block swizzle (T1, validated R22: -47us) ----
  const int lin = blockIdx.x + 8 * (blockIdx.y + 16 * blockIdx.z);
  const int j = ((lin & 7) << 5) | (lin >> 3);
  const int bz = j >> 7;         // batch
  const int by = (j >> 3) & 15;  // tile row
  const int bx = j & 7;          // tile col

  const int tid = threadIdx.x;
  const int r = tid / 24;        // region row 0..31
  const int c = (tid % 24) * 2;  // region col (float2-aligned)
  const int rc = r * RC + c;

  const int gi = by * TILE_R + r - HALO;  // global row (may be OOB)
  const int gj = bx * TILE_C + c - HALO;  // global col (even)
  const bool inImg = ((unsigned)gi < 256u) && ((unsigned)gj < 256u);
  const int base = bz * 65536 + gi * 256 + gj;

  // Interior block: whole region inside (0,255) in both dims -> masks all 1.
  const bool interior = (bx >= 1) && (bx <= 6) && (by >= 1) && (by <= 14);

  const float alpha0 = rp[0];
  const float alpha1 = rp[1];

  // ---- boundary masks as 0/1 multipliers (thread-constant) ----
  const float mD = (gi != 255) ? 1.f : 0.f;  // has down neighbor (H fwd)
  const float mU = (gi != 0) ? 1.f : 0.f;    // has up neighbor (H bwd)
  v2f mR, mL;
  mR.x = (gj + 0 != 255) ? 1.f : 0.f;
  mR.y = (gj + 1 != 255) ? 1.f : 0.f;
  mL.x = (gj != 0) ? 1.f : 0.f;
  mL.y = 1.f;

  // state: one packed v2f per field
  v2f u_, ub_, v1_, v2_, vb1_, vb2_, p1_, p2_, q11_, q22_, q12_, f_;

// paired load/store: [A(x),B(x),A(x+1),B(x+1)] at 2*base (16B aligned)
#define LOADP(va, vb, src)                    \
  {                                           \
    const float4 t4 = ld4((src) + 2 * base);  \
    va.x = t4.x; vb.x = t4.y;                 \
    va.y = t4.z; vb.y = t4.w;                 \
  }
  if (inImg) {
    f_ = *reinterpret_cast<const v2f*>(f + base);
    if (t0 == 0) {
      // PDHG initial state: u = ub = f, everything else zero.
      u_ = f_; ub_ = f_;
      v1_ = 0.f; v2_ = 0.f; vb1_ = 0.f; vb2_ = 0.f;
      p1_ = 0.f; p2_ = 0.f; q11_ = 0.f; q22_ = 0.f; q12_ = 0.f;
    } else {
      LOADP(ub_, q12_, pr3)   // dual-critical fields first
      LOADP(vb1_, vb2_, pr0)
      LOADP(p1_, p2_, pr1)
      LOADP(q11_, q22_, pr2)
      u_ = *reinterpret_cast<const v2f*>(ug + base);  // primal-only
      LOADP(v1_, v2_, pr4)                            // primal-only
    }
  } else {
    f_ = 0.f; u_ = 0.f; ub_ = 0.f;
    v1_ = 0.f; v2_ = 0.f; vb1_ = 0.f; vb2_ = 0.f;
    p1_ = 0.f; p2_ = 0.f; q11_ = 0.f; q22_ = 0.f; q12_ = 0.f;
  }
#undef LOADP

  // Loop-invariant hoist (bit-exact: identical expression, computed once).
  const v2f fI = kTau * f_;

  if (interior) {
    run8<false>(ubB0, ubB1, vbB0, vbB1, p1S, p2S, q11S, q22S, q12S, rc, r,
                alpha0, alpha1, mD, mU, mR, mL, fI, u_, ub_, v1_, v2_, vb1_,
                vb2_, p1_, p2_, q11_, q22_, q12_);
  } else {
    run8<true>(ubB0, ubB1, vbB0, vbB1, p1S, p2S, q11S, q22S, q12S, rc, r,
               alpha0, alpha1, mD, mU, mR, mL, fI, u_, ub_, v1_, v2_, vb1_,
               vb2_, p1_, p2_, q11_, q22_, q12_);
  }

  // ---- store interior 16x32 (exact after 8 iters) ----
  if (r >= HALO && r < HALO + TILE_R && c >= HALO && c < HALO + TILE_C) {
#define STOREP(va, vb, dst)                              \
  {                                                      \
    float4 t4;                                           \
    t4.x = va.x; t4.y = vb.x; t4.z = va.y; t4.w = vb.y;  \
    *reinterpret_cast<float4*>((dst) + 2 * base) = t4;   \
  }
    *reinterpret_cast<v2f*>(ug + base) = u_;
    if (t0 != NLAUNCH - 1) {  // ws is dead after the final launch
      STOREP(vb1_, vb2_, pr0)
      STOREP(p1_, p2_, pr1)
      STOREP(q11_, q22_, pr2)
      STOREP(ub_, q12_, pr3)
      STOREP(v1_, v2_, pr4)
    }
#undef STOREP
  }
}

}  // namespace

extern "C" void kernel_launch(void* const* d_in, const int* in_sizes, int n_in,
                              void* d_out, int out_size, void* d_ws,
                              size_t ws_size, hipStream_t stream) {
  const float* f = (const float*)d_in[0];
  const float* rp = (const float*)d_in[1];  // [alpha0, alpha1]
  // d_in[2] is T = 128 (fixed; trip count must be static for graph capture).

  float* u = (float*)d_out;
  float* ws = (float*)d_ws;

  dim3 grid(256 / TILE_C, 256 / TILE_R, 2);  // 8 x 16 x 2 = 256 blocks
  for (int t = 0; t < NLAUNCH; ++t) {        // 16 launches x 8 iterations
    hipLaunchKernelGGL(tgv8_kernel, grid, dim3(NTHREADS), 0, stream, f, rp, u,
                       ws, t);
  }
}

// Round 13
// 198.942 us; speedup vs baseline: 1.1810x; 1.0295x over previous
//
#include <hip/hip_runtime.h>
#include <math.h>

// TGV-2 PDHG, B=2, H=W=256, T=128.
// R26 = R23 verbatim (best measured: 199.6us, absmax 7.45e-9). R25's
// publish-fold (+5.2us) and R24's flag-sync (+35us) both regressed ->
// reverting to the best configuration.
// Final lever ledger (all measured on this structure):
//   ops -25%: null (R20) | DS instrs -24%: null/worse (R12)
//   off-path work -18%: null (R14) | in-block TLP 2x: +6% (R11)
//   2 blocks/CU: net worse, redundancy-dominated (R19)
//   flag-sync for s_barrier: +35us (R24) | 1-barrier via recompute: +25% (R21)
//   publish-fold into primal: +5us (R25) | wave-autonomous/DPP: >=50% worse
//   persistent kernel: 4x worse (prior session)
//   XCD swizzle: -47us WIN (R22) | paired-field handoff: -6us WIN (R23)
// Budget: exec ~154us (128 serial iters x ~1.2us mixed LDS-throughput/
// issue/latency floor) + 16 x ~2.9us launch-fixed. HALO=4/16 variants priced
// with measured F: wash or infeasible. Every neighbor measured/priced worse.
// Config: 16 launches x 8 trapezoid iters, region 32x48 (tile 16x32, halo
// 8), 256 blocks (1/CU), 768 threads (12 waves), packed v2f math, rsq+min
// projection, row gating, interior-maskless body (bit-exact), tau*f hoist,
// XCD swizzle j=(i%8)*32+i/8, paired-field ws layout, init folded into
// launch 0, final launch stores only u.

namespace {

typedef float v2f __attribute__((ext_vector_type(2)));

constexpr int kN = 2 * 256 * 256;
constexpr float kTau = 0.28867513459481287f;  // 1/sqrt(12) (f32)
constexpr float kSigma = kTau;
constexpr float kInv1pTau = 1.0f / (1.0f + kTau);

constexpr int RR = 32;          // region rows (H)
constexpr int RC = 48;          // region cols (W)
constexpr int A = RR * RC;      // 1536 floats per LDS array
constexpr int PAD = 64;         // rim-overread safety pads (front/back)
constexpr int TILE_R = 16;
constexpr int TILE_C = 32;
constexpr int HALO = 8;         // = iterations per launch
constexpr int NLAUNCH = 128 / HALO;      // 16
constexpr int NTHREADS = RR * (RC / 2);  // 768 = 12 waves

__device__ __forceinline__ float4 ld4(const float* p) {
  return *reinterpret_cast<const float4*>(p);
}

// The 8-iteration trapezoid loop. M=true: boundary blocks (image-edge masks
// as 0/1 multipliers). M=false: interior blocks — every mask is 1.0,
// multiplies removed (bit-exact: x*1.0f == x, no reassociation).
template <bool M>
__device__ __forceinline__ void run8(
    float* ubS, float* vbS, float* p1S, float* p2S, float* q11S, float* q22S,
    float* q12S, const int rc, const int r, const float alpha0,
    const float alpha1, const float mD, const float mU, const v2f mR,
    const v2f mL, const v2f fI, v2f& u_, v2f& ub_, v2f& v1_, v2f& v2_,
    v2f& vb1_, v2f& vb2_, v2f& p1_, v2f& p2_, v2f& q11_, v2f& q22_,
    v2f& q12_) {
  for (int t = 0; t < HALO; ++t) {
    // Active-set gating (row-wise, wave-granular) — measured-neutral, never
    // harmful; rows outside the sets are never read by valid outputs.
    const bool pubD = (r >= t) && (r <= 31 - t);
    const bool actD = (r >= t) && (r <= 30 - t);
    const bool actP = (r >= t + 1) && (r <= 30 - t);

    // ---- publish dual halos: ub (b64), vb pair (b128) ----
    if (pubD) {
      *reinterpret_cast<v2f*>(ubS + rc) = ub_;
      float4 vp;
      vp.x = vb1_.x; vp.y = vb2_.x; vp.z = vb1_.y; vp.w = vb2_.y;
      *reinterpret_cast<float4*>(vbS + 2 * rc) = vp;
    }
    __syncthreads();

    if (actD) {
      // ---- dual ascent + projections ----
      const float ubX = ubS[rc + 2];  // right-edge scalar neighbor
      const v2f vbX = *reinterpret_cast<const v2f*>(vbS + 2 * (rc + 2));
      const v2f ubD = *reinterpret_cast<const v2f*>(ubS + rc + RC);
      const float4 vd = ld4(vbS + 2 * (rc + RC));
      v2f vb1D, vb2D;
      vb1D.x = vd.x; vb1D.y = vd.z;
      vb2D.x = vd.y; vb2D.y = vd.w;

      v2f ubr, vb1r, vb2r;  // right-shifted (element e+1)
      ubr.x = ub_.y;   ubr.y = ubX;
      vb1r.x = vb1_.y; vb1r.y = vbX.x;
      vb2r.x = vb2_.y; vb2r.y = vbX.y;

      // p update
      const v2f du1 = M ? mD * (ubD - ub_) : (ubD - ub_);
      const v2f du2 = M ? mR * (ubr - ub_) : (ubr - ub_);
      const v2f pn1 = p1_ + kSigma * (du1 - vb1_);
      const v2f pn2 = p2_ + kSigma * (du2 - vb2_);
      const v2f n2p = pn1 * pn1 + pn2 * pn2;
      v2f sp;
      sp.x = fminf(1.f, alpha1 * __builtin_amdgcn_rsqf(n2p.x));
      sp.y = fminf(1.f, alpha1 * __builtin_amdgcn_rsqf(n2p.y));
      p1_ = pn1 * sp;
      p2_ = pn2 * sp;

      // q update (e11, e22, e12)
      const v2f e11 = M ? mD * (vb1D - vb1_) : (vb1D - vb1_);
      const v2f e22 = M ? mR * (vb2r - vb2_) : (vb2r - vb2_);
      const v2f e12 = M ? 0.5f * (mR * (vb1r - vb1_) + mD * (vb2D - vb2_))
                        : 0.5f * ((vb1r - vb1_) + (vb2D - vb2_));
      const v2f qn1 = q11_ + kSigma * e11;
      const v2f qn2 = q22_ + kSigma * e22;
      const v2f qn3 = q12_ + kSigma * e12;
      const v2f n2q = qn1 * qn1 + qn2 * qn2 + 2.f * (qn3 * qn3);
      v2f sq;
      sq.x = fminf(1.f, alpha0 * __builtin_amdgcn_rsqf(n2q.x));
      sq.y = fminf(1.f, alpha0 * __builtin_amdgcn_rsqf(n2q.y));
      q11_ = qn1 * sq;
      q22_ = qn2 * sq;
      q12_ = qn3 * sq;

      // ---- publish primal halos (new p, q) ----
      *reinterpret_cast<v2f*>(p1S + rc) = p1_;
      *reinterpret_cast<v2f*>(p2S + rc) = p2_;
      *reinterpret_cast<v2f*>(q11S + rc) = q11_;
      *reinterpret_cast<v2f*>(q22S + rc) = q22_;
      *reinterpret_cast<v2f*>(q12S + rc) = q12_;
    }
    __syncthreads();

    if (actP) {
      // ---- primal descent + over-relaxation ----
      const v2f p1U = *reinterpret_cast<const v2f*>(p1S + rc - RC);
      const v2f q11U = *reinterpret_cast<const v2f*>(q11S + rc - RC);
      const v2f q12U = *reinterpret_cast<const v2f*>(q12S + rc - RC);
      const float p2Ls = p2S[rc - 1];   // left-edge scalar neighbors
      const float q22Ls = q22S[rc - 1];
      const float q12Ls = q12S[rc - 1];

      v2f p2l, q22l, q12l;  // left-shifted (element e-1)
      p2l.x = p2Ls;   p2l.y = p2_.x;
      q22l.x = q22Ls; q22l.y = q22_.x;
      q12l.x = q12Ls; q12l.y = q12_.x;

      const v2f divp = M ? (mD * p1_ + mR * p2_ - (mU * p1U + mL * p2l))
                         : (p1_ + p2_ - (p1U + p2l));
      const v2f un = (u_ + kTau * divp + fI) * kInv1pTau;
      ub_ = 2.f * un - u_;
      u_ = un;

      const v2f c1 = M ? (mD * q11_ + mR * q12_ - (mU * q11U + mL * q12l))
                       : (q11_ + q12_ - (q11U + q12l));
      const v2f c2 = M ? (mD * q12_ + mR * q22_ - (mU * q12U + mL * q22l))
                       : (q12_ + q22_ - (q12U + q22l));
      const v2f v1n = v1_ + kTau * (p1_ + c1);
      const v2f v2n = v2_ + kTau * (p2_ + c2);
      vb1_ = 2.f * v1n - v1_;
      v1_ = v1n;
      vb2_ = 2.f * v2n - v2_;
      v2_ = v2n;
    }
  }
}

// ws layout: 5 pair-arrays of 2*kN floats, interleaved per pixel:
//   pr0=(vb1,vb2) pr1=(p1,p2) pr2=(q11,q22) pr3=(ub,q12) pr4=(v1,v2)
// u lives in ug (d_out) as before; f is the read-only input.
__global__ __launch_bounds__(NTHREADS, 3) void tgv8_kernel(
    const float* __restrict__ f, const float* __restrict__ rp,
    float* __restrict__ ug, float* __restrict__ ws, int t0) {
  float* pr0 = ws + 0 * 2 * kN;  // vb1, vb2
  float* pr1 = ws + 1 * 2 * kN;  // p1, p2
  float* pr2 = ws + 2 * 2 * kN;  // q11, q22
  float* pr3 = ws + 3 * 2 * kN;  // ub, q12
  float* pr4 = ws + 4 * 2 * kN;  // v1, v2

  // LDS: ub (A) + vb-pair (2A) + p1,p2,q11,q22,q12 (5A) = 8A floats
  __shared__ __align__(16) float smem[PAD + 8 * A + PAD];
  float* ubS = smem + PAD;
  float* vbS = ubS + A;       // interleaved [vb1, vb2] per pixel, 2A floats
  float* p1S = vbS + 2 * A;
  float* p2S = p1S + A;
  float* q11S = p2S + A;
  float* q22S = q11S + A;
  float* q12S = q22S + A;

  // ---- XCD-aware block swizzle (T1, validated R22: -47us) ----
  const int lin = blockIdx.x + 8 * (blockIdx.y + 16 * blockIdx.z);
  const int j = ((lin & 7) << 5) | (lin >> 3);
  const int bz = j >> 7;         // batch
  const int by = (j >> 3) & 15;  // tile row
  const int bx = j & 7;          // tile col

  const int tid = threadIdx.x;
  const int r = tid / 24;        // region row 0..31
  const int c = (tid % 24) * 2;  // region col (float2-aligned)
  const int rc = r * RC + c;

  const int gi = by * TILE_R + r - HALO;  // global row (may be OOB)
  const int gj = bx * TILE_C + c - HALO;  // global col (even)
  const bool inImg = ((unsigned)gi < 256u) && ((unsigned)gj < 256u);
  const int base = bz * 65536 + gi * 256 + gj;

  // Interior block: whole region inside (0,255) in both dims -> masks all 1.
  const bool interior = (bx >= 1) && (bx <= 6) && (by >= 1) && (by <= 14);

  const float alpha0 = rp[0];
  const float alpha1 = rp[1];

  // ---- boundary masks as 0/1 multipliers (thread-constant) ----
  const float mD = (gi != 255) ? 1.f : 0.f;  // has down neighbor (H fwd)
  const float mU = (gi != 0) ? 1.f : 0.f;    // has up neighbor (H bwd)
  v2f mR, mL;
  mR.x = (gj + 0 != 255) ? 1.f : 0.f;
  mR.y = (gj + 1 != 255) ? 1.f : 0.f;
  mL.x = (gj != 0) ? 1.f : 0.f;
  mL.y = 1.f;

  // state: one packed v2f per field
  v2f u_, ub_, v1_, v2_, vb1_, vb2_, p1_, p2_, q11_, q22_, q12_, f_;

// paired load/store: [A(x),B(x),A(x+1),B(x+1)] at 2*base (16B aligned)
#define LOADP(va, vb, src)                    \
  {                                           \
    const float4 t4 = ld4((src) + 2 * base);  \
    va.x = t4.x; vb.x = t4.y;                 \
    va.y = t4.z; vb.y = t4.w;                 \
  }
  if (inImg) {
    f_ = *reinterpret_cast<const v2f*>(f + base);
    if (t0 == 0) {
      // PDHG initial state: u = ub = f, everything else zero.
      u_ = f_; ub_ = f_;
      v1_ = 0.f; v2_ = 0.f; vb1_ = 0.f; vb2_ = 0.f;
      p1_ = 0.f; p2_ = 0.f; q11_ = 0.f; q22_ = 0.f; q12_ = 0.f;
    } else {
      LOADP(ub_, q12_, pr3)   // dual-critical fields first
      LOADP(vb1_, vb2_, pr0)
      LOADP(p1_, p2_, pr1)
      LOADP(q11_, q22_, pr2)
      u_ = *reinterpret_cast<const v2f*>(ug + base);  // primal-only
      LOADP(v1_, v2_, pr4)                            // primal-only
    }
  } else {
    f_ = 0.f; u_ = 0.f; ub_ = 0.f;
    v1_ = 0.f; v2_ = 0.f; vb1_ = 0.f; vb2_ = 0.f;
    p1_ = 0.f; p2_ = 0.f; q11_ = 0.f; q22_ = 0.f; q12_ = 0.f;
  }
#undef LOADP

  // Loop-invariant hoist (bit-exact: identical expression, computed once).
  const v2f fI = kTau * f_;

  if (interior) {
    run8<false>(ubS, vbS, p1S, p2S, q11S, q22S, q12S, rc, r, alpha0, alpha1,
                mD, mU, mR, mL, fI, u_, ub_, v1_, v2_, vb1_, vb2_, p1_, p2_,
                q11_, q22_, q12_);
  } else {
    run8<true>(ubS, vbS, p1S, p2S, q11S, q22S, q12S, rc, r, alpha0, alpha1,
               mD, mU, mR, mL, fI, u_, ub_, v1_, v2_, vb1_, vb2_, p1_, p2_,
               q11_, q22_, q12_);
  }

  // ---- store interior 16x32 (exact after 8 iters) ----
  if (r >= HALO && r < HALO + TILE_R && c >= HALO && c < HALO + TILE_C) {
#define STOREP(va, vb, dst)                              \
  {                                                      \
    float4 t4;                                           \
    t4.x = va.x; t4.y = vb.x; t4.z = va.y; t4.w = vb.y;  \
    *reinterpret_cast<float4*>((dst) + 2 * base) = t4;   \
  }
    *reinterpret_cast<v2f*>(ug + base) = u_;
    if (t0 != NLAUNCH - 1) {  // ws is dead after the final launch
      STOREP(vb1_, vb2_, pr0)
      STOREP(p1_, p2_, pr1)
      STOREP(q11_, q22_, pr2)
      STOREP(ub_, q12_, pr3)
      STOREP(v1_, v2_, pr4)
    }
#undef STOREP
  }
}

}  // namespace

extern "C" void kernel_launch(void* const* d_in, const int* in_sizes, int n_in,
                              void* d_out, int out_size, void* d_ws,
                              size_t ws_size, hipStream_t stream) {
  const float* f = (const float*)d_in[0];
  const float* rp = (const float*)d_in[1];  // [alpha0, alpha1]
  // d_in[2] is T = 128 (fixed; trip count must be static for graph capture).

  float* u = (float*)d_out;
  float* ws = (float*)d_ws;

  dim3 grid(256 / TILE_C, 256 / TILE_R, 2);  // 8 x 16 x 2 = 256 blocks
  for (int t = 0; t < NLAUNCH; ++t) {        // 16 launches x 8 iterations
    hipLaunchKernelGGL(tgv8_kernel, grid, dim3(NTHREADS), 0, stream, f, rp, u,
                       ws, t);
  }
}